// Round 2
// baseline (12981.737 us; speedup 1.0000x reference)
//
#include <hip/hip_runtime.h>
#include <hip/hip_bf16.h>

#define NN 50000
#define EE 1600000

using bf16 = __hip_bfloat16;

__device__ __forceinline__ float cvt_load(const void* p, int i, bool f32) {
    if (f32) return ((const float*)p)[i];
    unsigned short u = ((const unsigned short*)p)[i];
    return __uint_as_float((unsigned)u << 16);
}

// ---------------- dtype detection (runs every call; writes flags) ----------------
// flags[0] = edge_index is int64;  flags[1] = float tensors are f32
__global__ void detect_k(const void* ei_raw, const void* x_raw, int* flags) {
    __shared__ int s_i64, s_f32;
    const int t = threadIdx.x;
    if (t == 0) { s_i64 = 1; s_f32 = 0; }
    __syncthreads();
    const int* ei32 = (const int*)ei_raw;
    // int64 node ids < 2^31: every odd int32 word is 0. For int32 data these are
    // real node ids — all-zero over 256 samples is impossible in practice.
    if (ei32[2 * t + 1] != 0) atomicAnd(&s_i64, 0);
    // f32 data read as bf16: low half-words have random exponent fields ->
    // NaN/Inf patterns (P~2^-8/elem). Genuine bf16 inputs are finite.
    const unsigned short* xu = (const unsigned short*)x_raw;
    int found = 0;
    for (int j = 0; j < 32; j++) {
        unsigned short u = xu[t * 32 + j];
        if ((u & 0x7F80) == 0x7F80) found = 1;
    }
    if (found) atomicOr(&s_f32, 1);
    __syncthreads();
    if (t == 0) { flags[0] = s_i64; flags[1] = s_f32; }
}

// ---------------- edge list normalize -> int2 (src,dst) ----------------
__global__ __launch_bounds__(256) void repack_k(const void* ei_raw, int2* edges,
                                                const int* flags) {
    const int e = blockIdx.x * 256 + threadIdx.x;   // E exact
    const int i64 = __builtin_amdgcn_readfirstlane(flags[0]);
    int2 v;
    if (i64) {
        const long long* p = (const long long*)ei_raw;
        v.x = (int)p[e]; v.y = (int)p[EE + e];
    } else {
        const int* p = (const int*)ei_raw;
        v.x = p[e]; v.y = p[EE + e];
    }
    edges[e] = v;
}

// ---------------- float tensors normalize -> f32 workspace ----------------
__global__ __launch_bounds__(256) void cvt_all_k(
    const void* x, const void* W1, const void* Wskip, const void* W2, const void* W3,
    const void* as1, const void* ad1, const void* b1, const void* l1w, const void* l1b,
    const void* bsk, const void* as2, const void* ad2, const void* b2, const void* l2w,
    const void* l2b, const void* as3, const void* ad3, const void* b3,
    float* xin, float* wcvt, const int* flags)
{
    const bool f32 = __builtin_amdgcn_readfirstlane(flags[1]) != 0;
    const int gid = blockIdx.x * 256 + threadIdx.x;
    if (gid < NN * 128) { xin[gid] = cvt_load(x, gid, f32); return; }
    const int g = gid - NN * 128;
    if (g >= 83904) return;
    const void* src; int off;
    if      (g < 16384) { src = W1;    off = g;         }
    else if (g < 32768) { src = Wskip; off = g - 16384; }
    else if (g < 49152) { src = W2;    off = g - 32768; }
    else if (g < 81920) { src = W3;    off = g - 49152; }
    else {
        const int g0 = g - 81920;
        if      (g0 < 128)  { src = as1; off = g0;        }
        else if (g0 < 256)  { src = ad1; off = g0 - 128;  }
        else if (g0 < 384)  { src = b1;  off = g0 - 256;  }
        else if (g0 < 512)  { src = l1w; off = g0 - 384;  }
        else if (g0 < 640)  { src = l1b; off = g0 - 512;  }
        else if (g0 < 768)  { src = bsk; off = g0 - 640;  }
        else if (g0 < 896)  { src = as2; off = g0 - 768;  }
        else if (g0 < 1024) { src = ad2; off = g0 - 896;  }
        else if (g0 < 1152) { src = b2;  off = g0 - 1024; }
        else if (g0 < 1280) { src = l2w; off = g0 - 1152; }
        else if (g0 < 1408) { src = l2b; off = g0 - 1280; }
        else if (g0 < 1664) { src = as3; off = g0 - 1408; }
        else if (g0 < 1920) { src = ad3; off = g0 - 1664; }
        else                { src = b3;  off = g0 - 1920; }
    }
    wcvt[g] = cvt_load(src, off, f32);
}

// ---------------- dense matmul (FIN=128) + fused attention dots ----------------
template<int FOUT, int C, bool ATT>
__global__ __launch_bounds__(256) void matmul_k(
    const float* __restrict__ X, const float* __restrict__ W,
    const float* __restrict__ a_src, const float* __restrict__ a_dst,
    float* __restrict__ H, float* __restrict__ as_, float* __restrict__ ad_)
{
    constexpr int TPR  = FOUT / 4;     // threads per row (32 or 64)
    constexpr int ROWS = 256 / TPR;    // rows per block (8 or 4)
    __shared__ float xs[ROWS * 128];
    const int t = threadIdx.x;
    const int row0 = blockIdx.x * ROWS;
    for (int i = t; i < ROWS * 128; i += 256)
        xs[i] = X[(size_t)row0 * 128 + i];
    __syncthreads();

    const int tx = t % TPR, ty = t / TPR;
    const int row = row0 + ty;
    float a0 = 0.f, a1 = 0.f, a2 = 0.f, a3 = 0.f;
    #pragma unroll 4
    for (int k = 0; k < 128; k++) {
        const float xv = xs[ty * 128 + k];
        const float4 wv = *(const float4*)(W + (size_t)k * FOUT + tx * 4);
        a0 = fmaf(xv, wv.x, a0);
        a1 = fmaf(xv, wv.y, a1);
        a2 = fmaf(xv, wv.z, a2);
        a3 = fmaf(xv, wv.w, a3);
    }
    float4 o; o.x = a0; o.y = a1; o.z = a2; o.w = a3;
    *(float4*)(H + (size_t)row * FOUT + tx * 4) = o;

    if (ATT) {
        const int h  = (tx * 4) / C;
        const int cl = tx * 4 - h * C;
        float ps = a0 * a_src[h * C + cl]     + a1 * a_src[h * C + cl + 1]
                 + a2 * a_src[h * C + cl + 2] + a3 * a_src[h * C + cl + 3];
        float pd = a0 * a_dst[h * C + cl]     + a1 * a_dst[h * C + cl + 1]
                 + a2 * a_dst[h * C + cl + 2] + a3 * a_dst[h * C + cl + 3];
        constexpr int G = C / 4;       // lanes per head group (8 or 16)
        #pragma unroll
        for (int off = G / 2; off > 0; off >>= 1) {
            ps += __shfl_down(ps, off, G);
            pd += __shfl_down(pd, off, G);
        }
        if ((t & (G - 1)) == 0) {
            as_[(size_t)row * 4 + h] = ps;
            ad_[(size_t)row * 4 + h] = pd;
        }
    }
}

// ---------------- edge pass 1: w = exp(leakyrelu(as[src]+ad[dst])), s[dst,h] += w ----------------
__global__ __launch_bounds__(256) void edge_w_k(
    const int2* __restrict__ edges, const float* __restrict__ as_,
    const float* __restrict__ ad_, float* __restrict__ w, float* __restrict__ s)
{
    const int gid = blockIdx.x * 256 + threadIdx.x;   // E*4 exact
    const int e = gid >> 2, h = gid & 3;
    const int2 ed = edges[e];
    float ev = as_[(size_t)ed.x * 4 + h] + ad_[(size_t)ed.y * 4 + h];
    ev = ev >= 0.f ? ev : 0.2f * ev;
    const float wv = __expf(ev);
    w[gid] = wv;
    atomicAdd(&s[(size_t)ed.y * 4 + h], wv);
}

// ---------------- alpha output write (f32) ----------------
__global__ __launch_bounds__(256) void alpha_k(
    const int2* __restrict__ edges, const float* __restrict__ w,
    const float* __restrict__ s, float* __restrict__ alpha_out)
{
    const int gid = blockIdx.x * 256 + threadIdx.x;   // E*4 exact
    const int e = gid >> 2, h = gid & 3;
    const int dst = edges[e].y;
    alpha_out[gid] = w[gid] / (s[(size_t)dst * 4 + h] + 1e-16f);
}

// ---------------- scatter messages, F=128 (layers 1,2) ----------------
__global__ __launch_bounds__(256) void scatter_k(
    const int2* __restrict__ edges, const float* __restrict__ w, const float* __restrict__ s,
    const float* __restrict__ H, float* __restrict__ agg)
{
    const int gid = blockIdx.x * 256 + threadIdx.x;   // E*32 exact
    const int e = gid >> 5, q = gid & 31;
    const int2 ed = edges[e];
    const int h = q >> 3;
    const float a = w[(size_t)e * 4 + h] / (s[(size_t)ed.y * 4 + h] + 1e-16f);
    const float4 hv = *(const float4*)(H + (size_t)ed.x * 128 + q * 4);
    float* base = agg + (size_t)ed.y * 128 + q * 4;
    atomicAdd(base + 0, a * hv.x);
    atomicAdd(base + 1, a * hv.y);
    atomicAdd(base + 2, a * hv.z);
    atomicAdd(base + 3, a * hv.w);
}

// ---------------- scatter messages, F=256 with head-mean fold (layer 3) ----------------
__global__ __launch_bounds__(256) void scatter3_k(
    const int2* __restrict__ edges, const float* __restrict__ w, const float* __restrict__ s,
    const float* __restrict__ H, float* __restrict__ agg64)
{
    const int gid = blockIdx.x * 256 + threadIdx.x;   // E*64 exact
    const int e = gid >> 6, q = gid & 63;
    const int2 ed = edges[e];
    const int h = q >> 4, c4 = q & 15;
    const float a = 0.25f * w[(size_t)e * 4 + h] / (s[(size_t)ed.y * 4 + h] + 1e-16f);
    const float4 hv = *(const float4*)(H + (size_t)ed.x * 256 + h * 64 + c4 * 4);
    float* base = agg64 + (size_t)ed.y * 64 + c4 * 4;
    atomicAdd(base + 0, a * hv.x);
    atomicAdd(base + 1, a * hv.y);
    atomicAdd(base + 2, a * hv.z);
    atomicAdd(base + 3, a * hv.w);
}

// ---------------- node epilogue: +b, ELU, LayerNorm, (+skip+bskip) ----------------
template<bool HAS_SKIP>
__global__ __launch_bounds__(256) void post_k(
    const float* __restrict__ agg, const float* __restrict__ b,
    const float* __restrict__ lnw, const float* __restrict__ lnb,
    const float* __restrict__ skip, const float* __restrict__ bskip,
    float* __restrict__ xout)
{
    const int t = threadIdx.x;
    const int node = blockIdx.x * 4 + (t >> 6);  // 12500 blocks * 4 = 50000
    const int lane = t & 63;
    const float* row = agg + (size_t)node * 128;
    float v0 = row[lane]      + b[lane];
    float v1 = row[64 + lane] + b[64 + lane];
    v0 = v0 > 0.f ? v0 : expm1f(v0);
    v1 = v1 > 0.f ? v1 : expm1f(v1);
    float s1 = v0 + v1, s2 = v0 * v0 + v1 * v1;
    #pragma unroll
    for (int m = 32; m; m >>= 1) { s1 += __shfl_xor(s1, m); s2 += __shfl_xor(s2, m); }
    const float mu   = s1 * (1.f / 128.f);
    const float var  = s2 * (1.f / 128.f) - mu * mu;
    const float rstd = rsqrtf(var + 1e-5f);
    float y0 = (v0 - mu) * rstd * lnw[lane]      + lnb[lane];
    float y1 = (v1 - mu) * rstd * lnw[64 + lane] + lnb[64 + lane];
    if (HAS_SKIP) {
        const float* sr = skip + (size_t)node * 128;
        y0 += sr[lane]      + bskip[lane];
        y1 += sr[64 + lane] + bskip[64 + lane];
    }
    xout[(size_t)node * 128 + lane]      = y0;
    xout[(size_t)node * 128 + 64 + lane] = y1;
}

// ---------------- final: out = agg64 + b3 (f32) ----------------
__global__ __launch_bounds__(256) void final_k(
    const float* __restrict__ agg64, const float* __restrict__ b3, float* __restrict__ out)
{
    const int gid = blockIdx.x * 256 + threadIdx.x;   // N*64 exact
    out[gid] = agg64[gid] + b3[gid & 63];
}

extern "C" void kernel_launch(void* const* d_in, const int* in_sizes, int n_in,
                              void* d_out, int out_size, void* d_ws, size_t ws_size,
                              hipStream_t stream)
{
    char* ws = (char*)d_ws;
    float* H     = (float*)(ws);                 // [N,256] f32 (layers 1/2 use [N,128])
    float* xin   = (float*)(ws + 25600000);      // [N,128] f32 — aliases H upper half (dead by layer 3)
    float* xcur  = (float*)(ws + 51200000);      // [N,128] f32
    float* skip  = (float*)(ws + 76800000);      // [N,128] f32
    float* agg   = (float*)(ws + 102400000);     // [N,128] f32 (layer3: [N,64])
    float* wbuf  = (float*)(ws + 128000000);     // [E,4]  f32
    float* asb   = (float*)(ws + 153600000);     // [N,4]  f32
    float* adb   = (float*)(ws + 154400000);     // [N,4]  f32
    float* sb    = (float*)(ws + 155200000);     // [N,4]  f32
    int2*  edges = (int2*)(ws + 156000000);      // [E] int2
    int*   flags = (int*)(ws + 168800000);       // [2]
    float* wcvt  = (float*)(ws + 168800064);     // 83904 f32

    // converted-weight sub-pointers (layout must match cvt_all_k)
    float* W1c  = wcvt;            float* Wsc  = wcvt + 16384;
    float* W2c  = wcvt + 32768;    float* W3c  = wcvt + 49152;
    float* as1c = wcvt + 81920;    float* ad1c = as1c + 128;
    float* b1c  = as1c + 256;      float* l1wc = as1c + 384;
    float* l1bc = as1c + 512;      float* bskc = as1c + 640;
    float* as2c = as1c + 768;      float* ad2c = as1c + 896;
    float* b2c  = as1c + 1024;     float* l2wc = as1c + 1152;
    float* l2bc = as1c + 1280;     float* as3c = as1c + 1408;
    float* ad3c = as1c + 1664;     float* b3c  = as1c + 1920;

    float* out = (float*)d_out;
    float* al1 = out + (size_t)NN * 64;
    float* al2 = al1 + (size_t)EE * 4;
    float* al3 = al2 + (size_t)EE * 4;

    // ---------------- dtype normalize ----------------
    detect_k<<<1, 256, 0, stream>>>(d_in[1], d_in[0], flags);
    repack_k<<<6250, 256, 0, stream>>>(d_in[1], edges, flags);
    cvt_all_k<<<25329, 256, 0, stream>>>(
        d_in[0], d_in[2], d_in[8], d_in[10], d_in[16],
        d_in[3], d_in[4], d_in[5], d_in[6], d_in[7],
        d_in[9], d_in[11], d_in[12], d_in[13], d_in[14], d_in[15],
        d_in[17], d_in[18], d_in[19],
        xin, wcvt, flags);

    // ---------------- layer 1 ----------------
    hipMemsetAsync(sb, 0, (size_t)NN * 4 * sizeof(float), stream);
    hipMemsetAsync(agg, 0, (size_t)NN * 128 * sizeof(float), stream);
    matmul_k<128, 32, true ><<<6250, 256, 0, stream>>>(xin, W1c, as1c, ad1c, H, asb, adb);
    matmul_k<128, 32, false><<<6250, 256, 0, stream>>>(xin, Wsc, nullptr, nullptr, skip, nullptr, nullptr);
    edge_w_k <<<25000, 256, 0, stream>>>(edges, asb, adb, wbuf, sb);
    alpha_k  <<<25000, 256, 0, stream>>>(edges, wbuf, sb, al1);
    scatter_k<<<200000, 256, 0, stream>>>(edges, wbuf, sb, H, agg);
    post_k<true><<<12500, 256, 0, stream>>>(agg, b1c, l1wc, l1bc, skip, bskc, xcur);

    // ---------------- layer 2 ----------------
    hipMemsetAsync(sb, 0, (size_t)NN * 4 * sizeof(float), stream);
    hipMemsetAsync(agg, 0, (size_t)NN * 128 * sizeof(float), stream);
    matmul_k<128, 32, true><<<6250, 256, 0, stream>>>(xcur, W2c, as2c, ad2c, H, asb, adb);
    edge_w_k <<<25000, 256, 0, stream>>>(edges, asb, adb, wbuf, sb);
    alpha_k  <<<25000, 256, 0, stream>>>(edges, wbuf, sb, al2);
    scatter_k<<<200000, 256, 0, stream>>>(edges, wbuf, sb, H, agg);
    post_k<false><<<12500, 256, 0, stream>>>(agg, b2c, l2wc, l2bc, nullptr, nullptr, xcur);

    // ---------------- layer 3 ----------------
    hipMemsetAsync(sb, 0, (size_t)NN * 4 * sizeof(float), stream);
    hipMemsetAsync(agg, 0, (size_t)NN * 64 * sizeof(float), stream);
    matmul_k<256, 64, true><<<12500, 256, 0, stream>>>(xcur, W3c, as3c, ad3c, H, asb, adb);
    edge_w_k  <<<25000, 256, 0, stream>>>(edges, asb, adb, wbuf, sb);
    alpha_k   <<<25000, 256, 0, stream>>>(edges, wbuf, sb, al3);
    scatter3_k<<<400000, 256, 0, stream>>>(edges, wbuf, sb, H, agg);
    final_k   <<<12500, 256, 0, stream>>>(agg, b3c, out);
}

// Round 3
// 1728.683 us; speedup vs baseline: 7.5096x; 7.5096x over previous
//
#include <hip/hip_runtime.h>
#include <hip/hip_bf16.h>

#define NN 50000
#define EE 1600000

using bf16 = __hip_bfloat16;

__device__ __forceinline__ float cvt_load(const void* p, int i, bool f32) {
    if (f32) return ((const float*)p)[i];
    unsigned short u = ((const unsigned short*)p)[i];
    return __uint_as_float((unsigned)u << 16);
}

// ---------------- dtype detection (runs every call; writes flags) ----------------
__global__ void detect_k(const void* ei_raw, const void* x_raw, int* flags) {
    __shared__ int s_i64, s_f32;
    const int t = threadIdx.x;
    if (t == 0) { s_i64 = 1; s_f32 = 0; }
    __syncthreads();
    const int* ei32 = (const int*)ei_raw;
    if (ei32[2 * t + 1] != 0) atomicAnd(&s_i64, 0);
    const unsigned short* xu = (const unsigned short*)x_raw;
    int found = 0;
    for (int j = 0; j < 32; j++) {
        unsigned short u = xu[t * 32 + j];
        if ((u & 0x7F80) == 0x7F80) found = 1;
    }
    if (found) atomicOr(&s_f32, 1);
    __syncthreads();
    if (t == 0) { flags[0] = s_i64; flags[1] = s_f32; }
}

// ---------------- edge normalize -> int2 (src,dst) + degree count ----------------
__global__ __launch_bounds__(256) void repack_k(const void* ei_raw, int2* edges,
                                                int* deg, const int* flags) {
    const int e = blockIdx.x * 256 + threadIdx.x;   // E exact
    const int i64 = __builtin_amdgcn_readfirstlane(flags[0]);
    int2 v;
    if (i64) {
        const long long* p = (const long long*)ei_raw;
        v.x = (int)p[e]; v.y = (int)p[EE + e];
    } else {
        const int* p = (const int*)ei_raw;
        v.x = p[e]; v.y = p[EE + e];
    }
    edges[e] = v;
    atomicAdd(&deg[v.y], 1);
}

// ---------------- CSR row offsets: single-block scan ----------------
__global__ __launch_bounds__(256) void scan_k(const int* __restrict__ deg,
                                              int* __restrict__ roff, int* __restrict__ cursor) {
    __shared__ int ps[256];
    const int t = threadIdx.x;
    const int CH = (NN + 255) / 256;       // 196
    const int lo = t * CH, hi = min(lo + CH, NN);
    int s = 0;
    for (int i = lo; i < hi; i++) s += deg[i];
    ps[t] = s;
    __syncthreads();
    for (int off = 1; off < 256; off <<= 1) {
        int v = (t >= off) ? ps[t - off] : 0;
        __syncthreads();
        ps[t] += v;
        __syncthreads();
    }
    int run = t ? ps[t - 1] : 0;
    for (int i = lo; i < hi; i++) { roff[i] = run; cursor[i] = run; run += deg[i]; }
}

// ---------------- CSR fill ----------------
__global__ __launch_bounds__(256) void fill_k(const int2* __restrict__ edges,
                                              int* cursor, int* __restrict__ eidx) {
    const int e = blockIdx.x * 256 + threadIdx.x;   // E exact
    const int d = edges[e].y;
    const int p = atomicAdd(&cursor[d], 1);
    eidx[p] = e;
}

// ---------------- float tensors normalize -> f32 workspace ----------------
__global__ __launch_bounds__(256) void cvt_all_k(
    const void* x, const void* W1, const void* Wskip, const void* W2, const void* W3,
    const void* as1, const void* ad1, const void* b1, const void* l1w, const void* l1b,
    const void* bsk, const void* as2, const void* ad2, const void* b2, const void* l2w,
    const void* l2b, const void* as3, const void* ad3, const void* b3,
    float* xin, float* wcvt, const int* flags)
{
    const bool f32 = __builtin_amdgcn_readfirstlane(flags[1]) != 0;
    const int gid = blockIdx.x * 256 + threadIdx.x;
    if (gid < NN * 128) { xin[gid] = cvt_load(x, gid, f32); return; }
    const int g = gid - NN * 128;
    if (g >= 83904) return;
    const void* src; int off;
    if      (g < 16384) { src = W1;    off = g;         }
    else if (g < 32768) { src = Wskip; off = g - 16384; }
    else if (g < 49152) { src = W2;    off = g - 32768; }
    else if (g < 81920) { src = W3;    off = g - 49152; }
    else {
        const int g0 = g - 81920;
        if      (g0 < 128)  { src = as1; off = g0;        }
        else if (g0 < 256)  { src = ad1; off = g0 - 128;  }
        else if (g0 < 384)  { src = b1;  off = g0 - 256;  }
        else if (g0 < 512)  { src = l1w; off = g0 - 384;  }
        else if (g0 < 640)  { src = l1b; off = g0 - 512;  }
        else if (g0 < 768)  { src = bsk; off = g0 - 640;  }
        else if (g0 < 896)  { src = as2; off = g0 - 768;  }
        else if (g0 < 1024) { src = ad2; off = g0 - 896;  }
        else if (g0 < 1152) { src = b2;  off = g0 - 1024; }
        else if (g0 < 1280) { src = l2w; off = g0 - 1152; }
        else if (g0 < 1408) { src = l2b; off = g0 - 1280; }
        else if (g0 < 1664) { src = as3; off = g0 - 1408; }
        else if (g0 < 1920) { src = ad3; off = g0 - 1664; }
        else                { src = b3;  off = g0 - 1920; }
    }
    wcvt[g] = cvt_load(src, off, f32);
}

// ---------------- dense matmul (FIN=128) + fused attention dots ----------------
template<int FOUT, int C, bool ATT>
__global__ __launch_bounds__(256) void matmul_k(
    const float* __restrict__ X, const float* __restrict__ W,
    const float* __restrict__ a_src, const float* __restrict__ a_dst,
    float* __restrict__ H, float* __restrict__ as_, float* __restrict__ ad_)
{
    constexpr int TPR  = FOUT / 4;     // threads per row (32 or 64)
    constexpr int ROWS = 256 / TPR;    // rows per block (8 or 4)
    __shared__ float xs[ROWS * 128];
    const int t = threadIdx.x;
    const int row0 = blockIdx.x * ROWS;
    for (int i = t; i < ROWS * 128; i += 256)
        xs[i] = X[(size_t)row0 * 128 + i];
    __syncthreads();

    const int tx = t % TPR, ty = t / TPR;
    const int row = row0 + ty;
    float a0 = 0.f, a1 = 0.f, a2 = 0.f, a3 = 0.f;
    #pragma unroll 4
    for (int k = 0; k < 128; k++) {
        const float xv = xs[ty * 128 + k];
        const float4 wv = *(const float4*)(W + (size_t)k * FOUT + tx * 4);
        a0 = fmaf(xv, wv.x, a0);
        a1 = fmaf(xv, wv.y, a1);
        a2 = fmaf(xv, wv.z, a2);
        a3 = fmaf(xv, wv.w, a3);
    }
    float4 o; o.x = a0; o.y = a1; o.z = a2; o.w = a3;
    *(float4*)(H + (size_t)row * FOUT + tx * 4) = o;

    if (ATT) {
        const int h  = (tx * 4) / C;
        const int cl = tx * 4 - h * C;
        float ps = a0 * a_src[h * C + cl]     + a1 * a_src[h * C + cl + 1]
                 + a2 * a_src[h * C + cl + 2] + a3 * a_src[h * C + cl + 3];
        float pd = a0 * a_dst[h * C + cl]     + a1 * a_dst[h * C + cl + 1]
                 + a2 * a_dst[h * C + cl + 2] + a3 * a_dst[h * C + cl + 3];
        constexpr int G = C / 4;       // lanes per head group (8 or 16)
        #pragma unroll
        for (int off = G / 2; off > 0; off >>= 1) {
            ps += __shfl_down(ps, off, G);
            pd += __shfl_down(pd, off, G);
        }
        if ((t & (G - 1)) == 0) {
            as_[(size_t)row * 4 + h] = ps;
            ad_[(size_t)row * 4 + h] = pd;
        }
    }
}

// ---------------- edge pass: w = exp(leakyrelu(as[src]+ad[dst])), no atomics ----------------
__global__ __launch_bounds__(256) void edge_w_k(
    const int2* __restrict__ edges, const float* __restrict__ as_,
    const float* __restrict__ ad_, float* __restrict__ w)
{
    const int gid = blockIdx.x * 256 + threadIdx.x;   // E*4 exact
    const int e = gid >> 2, h = gid & 3;
    const int2 ed = edges[e];
    float ev = as_[(size_t)ed.x * 4 + h] + ad_[(size_t)ed.y * 4 + h];
    ev = ev >= 0.f ? ev : 0.2f * ev;
    w[gid] = __expf(ev);
}

// ---------------- alpha output write (reads precomputed s) ----------------
__global__ __launch_bounds__(256) void alpha_k(
    const int2* __restrict__ edges, const float* __restrict__ w,
    const float* __restrict__ s, float* __restrict__ alpha_out)
{
    const int gid = blockIdx.x * 256 + threadIdx.x;   // E*4 exact
    const int e = gid >> 2, h = gid & 3;
    const int dst = edges[e].y;
    alpha_out[gid] = w[gid] / (s[(size_t)dst * 4 + h] + 1e-16f);
}

// ---------------- fused gather+softmax-denom+bias+ELU+LN(+skip), F=128 ----------------
// one wave per dst node; lane covers channels (2*lane, 2*lane+1)
template<bool HAS_SKIP>
__global__ __launch_bounds__(256) void gather12_k(
    const int* __restrict__ roff, const int* __restrict__ deg, const int* __restrict__ eidx,
    const int2* __restrict__ edges, const float* __restrict__ w, const float* __restrict__ H,
    float* __restrict__ s_out,
    const float* __restrict__ b, const float* __restrict__ lnw, const float* __restrict__ lnb,
    const float* __restrict__ skip, const float* __restrict__ bskip,
    float* __restrict__ xout)
{
    const int node = blockIdx.x * 4 + (threadIdx.x >> 6);   // 12500*4 = NN
    const int lane = threadIdx.x & 63;
    const int ro = roff[node], dg = deg[node];

    // ---- pass 1: s[h] = sum_e w[e][h] ----
    float4 sv = make_float4(0.f, 0.f, 0.f, 0.f);
    for (int j = lane; j < dg; j += 64) {
        const int eid = eidx[ro + j];
        const float4 wv = *(const float4*)(w + (size_t)eid * 4);
        sv.x += wv.x; sv.y += wv.y; sv.z += wv.z; sv.w += wv.w;
    }
    #pragma unroll
    for (int m = 32; m; m >>= 1) {
        sv.x += __shfl_xor(sv.x, m); sv.y += __shfl_xor(sv.y, m);
        sv.z += __shfl_xor(sv.z, m); sv.w += __shfl_xor(sv.w, m);
    }
    if (lane == 0) *(float4*)(s_out + (size_t)node * 4) = sv;
    const int h = lane >> 4;   // head of channels 2*lane, 2*lane+1
    const float sh  = (h == 0) ? sv.x : (h == 1) ? sv.y : (h == 2) ? sv.z : sv.w;
    const float rsh = 1.f / (sh + 1e-16f);

    // ---- pass 2: acc[c] = sum_e alpha[e][h] * H[src][c] ----
    float ax = 0.f, ay = 0.f;
    for (int j0 = 0; j0 < dg; j0 += 64) {
        const int jn = min(64, dg - j0);
        int eid = 0, src = 0;
        if (lane < jn) { eid = eidx[ro + j0 + lane]; src = edges[eid].x; }
        for (int j = 0; j < jn; j++) {
            const int e_ = __shfl(eid, j);
            const int s_ = __shfl(src, j);
            const float a = w[(size_t)e_ * 4 + h] * rsh;
            const float2 hv = *(const float2*)(H + (size_t)s_ * 128 + 2 * lane);
            ax = fmaf(a, hv.x, ax);
            ay = fmaf(a, hv.y, ay);
        }
    }

    // ---- epilogue: +b, ELU, LN, (+skip+bskip) ----
    float v0 = ax + b[2 * lane];
    float v1 = ay + b[2 * lane + 1];
    v0 = v0 > 0.f ? v0 : expm1f(v0);
    v1 = v1 > 0.f ? v1 : expm1f(v1);
    float s1 = v0 + v1, s2 = v0 * v0 + v1 * v1;
    #pragma unroll
    for (int m = 32; m; m >>= 1) { s1 += __shfl_xor(s1, m); s2 += __shfl_xor(s2, m); }
    const float mu   = s1 * (1.f / 128.f);
    const float var  = s2 * (1.f / 128.f) - mu * mu;
    const float rstd = rsqrtf(var + 1e-5f);
    float y0 = (v0 - mu) * rstd * lnw[2 * lane]     + lnb[2 * lane];
    float y1 = (v1 - mu) * rstd * lnw[2 * lane + 1] + lnb[2 * lane + 1];
    if (HAS_SKIP) {
        const float2 sk = *(const float2*)(skip + (size_t)node * 128 + 2 * lane);
        y0 += sk.x + bskip[2 * lane];
        y1 += sk.y + bskip[2 * lane + 1];
    }
    float2 o; o.x = y0; o.y = y1;
    *(float2*)(xout + (size_t)node * 128 + 2 * lane) = o;
}

// ---------------- fused gather, layer 3: F=256, head-mean, +b3 -> out ----------------
__global__ __launch_bounds__(256) void gather3_k(
    const int* __restrict__ roff, const int* __restrict__ deg, const int* __restrict__ eidx,
    const int2* __restrict__ edges, const float* __restrict__ w, const float* __restrict__ H,
    float* __restrict__ s_out, const float* __restrict__ b3, float* __restrict__ out)
{
    const int node = blockIdx.x * 4 + (threadIdx.x >> 6);
    const int lane = threadIdx.x & 63;   // output channel
    const int ro = roff[node], dg = deg[node];

    float4 sv = make_float4(0.f, 0.f, 0.f, 0.f);
    for (int j = lane; j < dg; j += 64) {
        const int eid = eidx[ro + j];
        const float4 wv = *(const float4*)(w + (size_t)eid * 4);
        sv.x += wv.x; sv.y += wv.y; sv.z += wv.z; sv.w += wv.w;
    }
    #pragma unroll
    for (int m = 32; m; m >>= 1) {
        sv.x += __shfl_xor(sv.x, m); sv.y += __shfl_xor(sv.y, m);
        sv.z += __shfl_xor(sv.z, m); sv.w += __shfl_xor(sv.w, m);
    }
    if (lane == 0) *(float4*)(s_out + (size_t)node * 4) = sv;
    float4 rs;
    rs.x = 0.25f / (sv.x + 1e-16f); rs.y = 0.25f / (sv.y + 1e-16f);
    rs.z = 0.25f / (sv.z + 1e-16f); rs.w = 0.25f / (sv.w + 1e-16f);

    float acc = 0.f;
    for (int j0 = 0; j0 < dg; j0 += 64) {
        const int jn = min(64, dg - j0);
        int eid = 0, src = 0;
        if (lane < jn) { eid = eidx[ro + j0 + lane]; src = edges[eid].x; }
        for (int j = 0; j < jn; j++) {
            const int e_ = __shfl(eid, j);
            const int s_ = __shfl(src, j);
            const float4 wv = *(const float4*)(w + (size_t)e_ * 4);
            const float* hr = H + (size_t)s_ * 256 + lane;
            acc = fmaf(wv.x * rs.x, hr[0],   acc);
            acc = fmaf(wv.y * rs.y, hr[64],  acc);
            acc = fmaf(wv.z * rs.z, hr[128], acc);
            acc = fmaf(wv.w * rs.w, hr[192], acc);
        }
    }
    out[(size_t)node * 64 + lane] = acc + b3[lane];
}

extern "C" void kernel_launch(void* const* d_in, const int* in_sizes, int n_in,
                              void* d_out, int out_size, void* d_ws, size_t ws_size,
                              hipStream_t stream)
{
    char* ws = (char*)d_ws;
    float* H      = (float*)(ws);                 // [N,256] f32 (layers 1/2 use [N,128])
    float* xin    = (float*)(ws + 25600000);      // [N,128] — aliases H upper half (dead by layer 3)
    float* xcur   = (float*)(ws + 51200000);      // [N,128]
    float* skip   = (float*)(ws + 76800000);      // [N,128]
    float* wbuf   = (float*)(ws + 102400000);     // [E,4]
    float* sb     = (float*)(ws + 128000000);     // [N,4]
    float* asb    = (float*)(ws + 128800000);     // [N,4]
    float* adb    = (float*)(ws + 129600000);     // [N,4]
    int2*  edges  = (int2*)(ws + 130400000);      // [E]
    int*   eidx   = (int*)(ws + 143200000);       // [E]
    int*   roff   = (int*)(ws + 149600000);       // [N]
    int*   deg    = (int*)(ws + 149800000);       // [N]
    int*   cursor = (int*)(ws + 150000000);       // [N]
    int*   flags  = (int*)(ws + 150200000);       // [2]
    float* wcvt   = (float*)(ws + 150200064);     // 83904 f32

    float* W1c  = wcvt;            float* Wsc  = wcvt + 16384;
    float* W2c  = wcvt + 32768;    float* W3c  = wcvt + 49152;
    float* as1c = wcvt + 81920;    float* ad1c = as1c + 128;
    float* b1c  = as1c + 256;      float* l1wc = as1c + 384;
    float* l1bc = as1c + 512;      float* bskc = as1c + 640;
    float* as2c = as1c + 768;      float* ad2c = as1c + 896;
    float* b2c  = as1c + 1024;     float* l2wc = as1c + 1152;
    float* l2bc = as1c + 1280;     float* as3c = as1c + 1408;
    float* ad3c = as1c + 1664;     float* b3c  = as1c + 1920;

    float* out = (float*)d_out;
    float* al1 = out + (size_t)NN * 64;
    float* al2 = al1 + (size_t)EE * 4;
    float* al3 = al2 + (size_t)EE * 4;

    // ---------------- normalize + CSR build (once per call) ----------------
    detect_k<<<1, 256, 0, stream>>>(d_in[1], d_in[0], flags);
    hipMemsetAsync(deg, 0, NN * sizeof(int), stream);
    repack_k<<<6250, 256, 0, stream>>>(d_in[1], edges, deg, flags);
    cvt_all_k<<<25329, 256, 0, stream>>>(
        d_in[0], d_in[2], d_in[8], d_in[10], d_in[16],
        d_in[3], d_in[4], d_in[5], d_in[6], d_in[7],
        d_in[9], d_in[11], d_in[12], d_in[13], d_in[14], d_in[15],
        d_in[17], d_in[18], d_in[19],
        xin, wcvt, flags);
    scan_k<<<1, 256, 0, stream>>>(deg, roff, cursor);
    fill_k<<<6250, 256, 0, stream>>>(edges, cursor, eidx);

    // ---------------- layer 1 ----------------
    matmul_k<128, 32, true ><<<6250, 256, 0, stream>>>(xin, W1c, as1c, ad1c, H, asb, adb);
    matmul_k<128, 32, false><<<6250, 256, 0, stream>>>(xin, Wsc, nullptr, nullptr, skip, nullptr, nullptr);
    edge_w_k<<<25000, 256, 0, stream>>>(edges, asb, adb, wbuf);
    gather12_k<true><<<12500, 256, 0, stream>>>(roff, deg, eidx, edges, wbuf, H, sb,
                                                b1c, l1wc, l1bc, skip, bskc, xcur);
    alpha_k<<<25000, 256, 0, stream>>>(edges, wbuf, sb, al1);

    // ---------------- layer 2 ----------------
    matmul_k<128, 32, true><<<6250, 256, 0, stream>>>(xcur, W2c, as2c, ad2c, H, asb, adb);
    edge_w_k<<<25000, 256, 0, stream>>>(edges, asb, adb, wbuf);
    gather12_k<false><<<12500, 256, 0, stream>>>(roff, deg, eidx, edges, wbuf, H, sb,
                                                 b2c, l2wc, l2bc, nullptr, nullptr, xcur);
    alpha_k<<<25000, 256, 0, stream>>>(edges, wbuf, sb, al2);

    // ---------------- layer 3 ----------------
    matmul_k<256, 64, true><<<12500, 256, 0, stream>>>(xcur, W3c, as3c, ad3c, H, asb, adb);
    edge_w_k<<<25000, 256, 0, stream>>>(edges, asb, adb, wbuf);
    gather3_k<<<12500, 256, 0, stream>>>(roff, deg, eidx, edges, wbuf, H, sb, b3c, out);
    alpha_k<<<25000, 256, 0, stream>>>(edges, wbuf, sb, al3);
}

// Round 4
// 1641.012 us; speedup vs baseline: 7.9108x; 1.0534x over previous
//
#include <hip/hip_runtime.h>

#define NN 50000
#define EE 1600000

__device__ __forceinline__ float bfu(unsigned short u) { return __uint_as_float((unsigned)u << 16); }
__device__ __forceinline__ unsigned short f2bf(float f) {   // RNE f32->bf16
    unsigned u = __float_as_uint(f);
    u += 0x7fff + ((u >> 16) & 1);
    return (unsigned short)(u >> 16);
}
__device__ __forceinline__ float cvt_load(const void* p, int i, bool f32) {
    if (f32) return ((const float*)p)[i];
    return bfu(((const unsigned short*)p)[i]);
}

// ---------------- dtype detection (runs every call; writes flags) ----------------
__global__ void detect_k(const void* ei_raw, const void* x_raw, int* flags) {
    __shared__ int s_i64, s_f32;
    const int t = threadIdx.x;
    if (t == 0) { s_i64 = 1; s_f32 = 0; }
    __syncthreads();
    const int* ei32 = (const int*)ei_raw;
    if (ei32[2 * t + 1] != 0) atomicAnd(&s_i64, 0);
    const unsigned short* xu = (const unsigned short*)x_raw;
    int found = 0;
    for (int j = 0; j < 32; j++) {
        unsigned short u = xu[t * 32 + j];
        if ((u & 0x7F80) == 0x7F80) found = 1;
    }
    if (found) atomicOr(&s_f32, 1);
    __syncthreads();
    if (t == 0) { flags[0] = s_i64; flags[1] = s_f32; }
}

// ---------------- edge normalize -> int2 (src,dst) + degree count ----------------
__global__ __launch_bounds__(256) void repack_k(const void* ei_raw, int2* edges,
                                                int* deg, const int* flags) {
    const int e = blockIdx.x * 256 + threadIdx.x;   // E exact
    const int i64 = __builtin_amdgcn_readfirstlane(flags[0]);
    int2 v;
    if (i64) {
        const long long* p = (const long long*)ei_raw;
        v.x = (int)p[e]; v.y = (int)p[EE + e];
    } else {
        const int* p = (const int*)ei_raw;
        v.x = p[e]; v.y = p[EE + e];
    }
    edges[e] = v;
    atomicAdd(&deg[v.y], 1);
}

// ---------------- CSR row offsets: single-block scan ----------------
__global__ __launch_bounds__(256) void scan_k(const int* __restrict__ deg,
                                              int* __restrict__ roff, int* __restrict__ cursor) {
    __shared__ int ps[256];
    const int t = threadIdx.x;
    const int CH = (NN + 255) / 256;
    const int lo = t * CH, hi = min(lo + CH, NN);
    int s = 0;
    for (int i = lo; i < hi; i++) s += deg[i];
    ps[t] = s;
    __syncthreads();
    for (int off = 1; off < 256; off <<= 1) {
        int v = (t >= off) ? ps[t - off] : 0;
        __syncthreads();
        ps[t] += v;
        __syncthreads();
    }
    int run = t ? ps[t - 1] : 0;
    for (int i = lo; i < hi; i++) { roff[i] = run; cursor[i] = run; run += deg[i]; }
}

// ---------------- CSR fill ----------------
__global__ __launch_bounds__(256) void fill_k(const int2* __restrict__ edges,
                                              int* cursor, int* __restrict__ eidx) {
    const int e = blockIdx.x * 256 + threadIdx.x;   // E exact
    const int d = edges[e].y;
    const int p = atomicAdd(&cursor[d], 1);
    eidx[p] = e;
}

// ---------------- float tensors normalize -> f32 workspace ----------------
__global__ __launch_bounds__(256) void cvt_all_k(
    const void* x, const void* W1, const void* Wskip, const void* W2, const void* W3,
    const void* as1, const void* ad1, const void* b1, const void* l1w, const void* l1b,
    const void* bsk, const void* as2, const void* ad2, const void* b2, const void* l2w,
    const void* l2b, const void* as3, const void* ad3, const void* b3,
    float* xin, float* wcvt, const int* flags)
{
    const bool f32 = __builtin_amdgcn_readfirstlane(flags[1]) != 0;
    const int gid = blockIdx.x * 256 + threadIdx.x;
    if (gid < NN * 128) { xin[gid] = cvt_load(x, gid, f32); return; }
    const int g = gid - NN * 128;
    if (g >= 83904) return;
    const void* src; int off;
    if      (g < 16384) { src = W1;    off = g;         }
    else if (g < 32768) { src = Wskip; off = g - 16384; }
    else if (g < 49152) { src = W2;    off = g - 32768; }
    else if (g < 81920) { src = W3;    off = g - 49152; }
    else {
        const int g0 = g - 81920;
        if      (g0 < 128)  { src = as1; off = g0;        }
        else if (g0 < 256)  { src = ad1; off = g0 - 128;  }
        else if (g0 < 384)  { src = b1;  off = g0 - 256;  }
        else if (g0 < 512)  { src = l1w; off = g0 - 384;  }
        else if (g0 < 640)  { src = l1b; off = g0 - 512;  }
        else if (g0 < 768)  { src = bsk; off = g0 - 640;  }
        else if (g0 < 896)  { src = as2; off = g0 - 768;  }
        else if (g0 < 1024) { src = ad2; off = g0 - 896;  }
        else if (g0 < 1152) { src = b2;  off = g0 - 1024; }
        else if (g0 < 1280) { src = l2w; off = g0 - 1152; }
        else if (g0 < 1408) { src = l2b; off = g0 - 1280; }
        else if (g0 < 1664) { src = as3; off = g0 - 1408; }
        else if (g0 < 1920) { src = ad3; off = g0 - 1664; }
        else                { src = b3;  off = g0 - 1920; }
    }
    wcvt[g] = cvt_load(src, off, f32);
}

// ---------------- dense matmul (FIN=128) + fused attention dots ----------------
// BF16OUT: store H as bf16 (f32 accumulate, RNE on store); else f32 (skip buffer)
template<int FOUT, int C, bool ATT, bool BF16OUT>
__global__ __launch_bounds__(256) void matmul_k(
    const float* __restrict__ X, const float* __restrict__ W,
    const float* __restrict__ a_src, const float* __restrict__ a_dst,
    void* __restrict__ Hout, float* __restrict__ as_, float* __restrict__ ad_)
{
    constexpr int TPR  = FOUT / 4;
    constexpr int ROWS = 256 / TPR;
    __shared__ float xs[ROWS * 128];
    const int t = threadIdx.x;
    const int row0 = blockIdx.x * ROWS;
    for (int i = t; i < ROWS * 128; i += 256)
        xs[i] = X[(size_t)row0 * 128 + i];
    __syncthreads();

    const int tx = t % TPR, ty = t / TPR;
    const int row = row0 + ty;
    float a0 = 0.f, a1 = 0.f, a2 = 0.f, a3 = 0.f;
    #pragma unroll 4
    for (int k = 0; k < 128; k++) {
        const float xv = xs[ty * 128 + k];
        const float4 wv = *(const float4*)(W + (size_t)k * FOUT + tx * 4);
        a0 = fmaf(xv, wv.x, a0);
        a1 = fmaf(xv, wv.y, a1);
        a2 = fmaf(xv, wv.z, a2);
        a3 = fmaf(xv, wv.w, a3);
    }
    if (BF16OUT) {
        ushort4 o;
        o.x = f2bf(a0); o.y = f2bf(a1); o.z = f2bf(a2); o.w = f2bf(a3);
        *(ushort4*)((unsigned short*)Hout + (size_t)row * FOUT + tx * 4) = o;
    } else {
        float4 o; o.x = a0; o.y = a1; o.z = a2; o.w = a3;
        *(float4*)((float*)Hout + (size_t)row * FOUT + tx * 4) = o;
    }

    if (ATT) {
        const int h  = (tx * 4) / C;
        const int cl = tx * 4 - h * C;
        float ps = a0 * a_src[h * C + cl]     + a1 * a_src[h * C + cl + 1]
                 + a2 * a_src[h * C + cl + 2] + a3 * a_src[h * C + cl + 3];
        float pd = a0 * a_dst[h * C + cl]     + a1 * a_dst[h * C + cl + 1]
                 + a2 * a_dst[h * C + cl + 2] + a3 * a_dst[h * C + cl + 3];
        constexpr int G = C / 4;
        #pragma unroll
        for (int off = G / 2; off > 0; off >>= 1) {
            ps += __shfl_down(ps, off, G);
            pd += __shfl_down(pd, off, G);
        }
        if ((t & (G - 1)) == 0) {
            as_[(size_t)row * 4 + h] = ps;
            ad_[(size_t)row * 4 + h] = pd;
        }
    }
}

// ---------------- fused per-layer edge phase, F=128 (layers 1,2) ----------------
// one wave per dst node: w=exp(lrelu(as[src]+ad[dst])), s-reduce, alpha write,
// gather bf16 H rows, then +b, ELU, LN, (+skip+bskip)
template<bool HAS_SKIP>
__global__ __launch_bounds__(256) void fgather12_k(
    const int* __restrict__ roff, const int* __restrict__ deg, const int* __restrict__ eidx,
    const int2* __restrict__ edges, const float* __restrict__ as_, const float* __restrict__ ad_,
    float* __restrict__ wbuf, const unsigned short* __restrict__ Hb,
    float* __restrict__ alpha_out,
    const float* __restrict__ b, const float* __restrict__ lnw, const float* __restrict__ lnb,
    const float* __restrict__ skip, const float* __restrict__ bskip,
    float* __restrict__ xout)
{
    const int node = blockIdx.x * 4 + (threadIdx.x >> 6);   // 12500*4 = NN
    const int lane = threadIdx.x & 63;
    const int ro = roff[node], dg = deg[node];
    const float4 ad4 = *(const float4*)(ad_ + (size_t)node * 4);

    // ---- pass 1: w per edge + s reduction ----
    float4 sv = make_float4(0.f, 0.f, 0.f, 0.f);
    for (int j = lane; j < dg; j += 64) {
        const int eid = eidx[ro + j];
        const int src = edges[eid].x;
        float4 e4 = *(const float4*)(as_ + (size_t)src * 4);
        e4.x += ad4.x; e4.y += ad4.y; e4.z += ad4.z; e4.w += ad4.w;
        e4.x = e4.x >= 0.f ? e4.x : 0.2f * e4.x;
        e4.y = e4.y >= 0.f ? e4.y : 0.2f * e4.y;
        e4.z = e4.z >= 0.f ? e4.z : 0.2f * e4.z;
        e4.w = e4.w >= 0.f ? e4.w : 0.2f * e4.w;
        float4 w4;
        w4.x = __expf(e4.x); w4.y = __expf(e4.y); w4.z = __expf(e4.z); w4.w = __expf(e4.w);
        *(float4*)(wbuf + (size_t)eid * 4) = w4;
        sv.x += w4.x; sv.y += w4.y; sv.z += w4.z; sv.w += w4.w;
    }
    #pragma unroll
    for (int m = 32; m; m >>= 1) {
        sv.x += __shfl_xor(sv.x, m); sv.y += __shfl_xor(sv.y, m);
        sv.z += __shfl_xor(sv.z, m); sv.w += __shfl_xor(sv.w, m);
    }
    __threadfence_block();   // wbuf stores visible to all lanes via CU L1
    float4 rs;
    rs.x = 1.f / (sv.x + 1e-16f); rs.y = 1.f / (sv.y + 1e-16f);
    rs.z = 1.f / (sv.z + 1e-16f); rs.w = 1.f / (sv.w + 1e-16f);

    // ---- alpha outputs ----
    for (int j = lane; j < dg; j += 64) {
        const int eid = eidx[ro + j];
        const float4 w4 = *(const float4*)(wbuf + (size_t)eid * 4);
        float4 a4;
        a4.x = w4.x * rs.x; a4.y = w4.y * rs.y; a4.z = w4.z * rs.z; a4.w = w4.w * rs.w;
        *(float4*)(alpha_out + (size_t)eid * 4) = a4;
    }

    // ---- pass 2: acc[c] = sum_e alpha[e][h(c)] * H[src][c] (bf16 rows) ----
    const int h = lane >> 4;
    const float rsh = (h == 0) ? rs.x : (h == 1) ? rs.y : (h == 2) ? rs.z : rs.w;
    float ax = 0.f, ay = 0.f;
    for (int j0 = 0; j0 < dg; j0 += 64) {
        const int jn = min(64, dg - j0);
        int eid = 0, src = 0;
        if (lane < jn) { eid = eidx[ro + j0 + lane]; src = edges[eid].x; }
        for (int j = 0; j < jn; j++) {
            const int e_ = __shfl(eid, j);
            const int s_ = __shfl(src, j);
            const float a = wbuf[(size_t)e_ * 4 + h] * rsh;
            const unsigned hv = *(const unsigned*)(Hb + (size_t)s_ * 128 + 2 * lane);
            ax = fmaf(a, bfu((unsigned short)hv), ax);
            ay = fmaf(a, bfu((unsigned short)(hv >> 16)), ay);
        }
    }

    // ---- epilogue ----
    float v0 = ax + b[2 * lane];
    float v1 = ay + b[2 * lane + 1];
    v0 = v0 > 0.f ? v0 : expm1f(v0);
    v1 = v1 > 0.f ? v1 : expm1f(v1);
    float s1 = v0 + v1, s2 = v0 * v0 + v1 * v1;
    #pragma unroll
    for (int m = 32; m; m >>= 1) { s1 += __shfl_xor(s1, m); s2 += __shfl_xor(s2, m); }
    const float mu   = s1 * (1.f / 128.f);
    const float var  = s2 * (1.f / 128.f) - mu * mu;
    const float rstd = rsqrtf(var + 1e-5f);
    float y0 = (v0 - mu) * rstd * lnw[2 * lane]     + lnb[2 * lane];
    float y1 = (v1 - mu) * rstd * lnw[2 * lane + 1] + lnb[2 * lane + 1];
    if (HAS_SKIP) {
        const float2 sk = *(const float2*)(skip + (size_t)node * 128 + 2 * lane);
        y0 += sk.x + bskip[2 * lane];
        y1 += sk.y + bskip[2 * lane + 1];
    }
    float2 o; o.x = y0; o.y = y1;
    *(float2*)(xout + (size_t)node * 128 + 2 * lane) = o;
}

// ---------------- fused edge phase, layer 3: F=256, head-mean, +b3 -> out ----------------
__global__ __launch_bounds__(256) void fgather3_k(
    const int* __restrict__ roff, const int* __restrict__ deg, const int* __restrict__ eidx,
    const int2* __restrict__ edges, const float* __restrict__ as_, const float* __restrict__ ad_,
    float* __restrict__ wbuf, const unsigned short* __restrict__ Hb,
    float* __restrict__ alpha_out, const float* __restrict__ b3, float* __restrict__ out)
{
    const int node = blockIdx.x * 4 + (threadIdx.x >> 6);
    const int lane = threadIdx.x & 63;   // output channel
    const int ro = roff[node], dg = deg[node];
    const float4 ad4 = *(const float4*)(ad_ + (size_t)node * 4);

    float4 sv = make_float4(0.f, 0.f, 0.f, 0.f);
    for (int j = lane; j < dg; j += 64) {
        const int eid = eidx[ro + j];
        const int src = edges[eid].x;
        float4 e4 = *(const float4*)(as_ + (size_t)src * 4);
        e4.x += ad4.x; e4.y += ad4.y; e4.z += ad4.z; e4.w += ad4.w;
        e4.x = e4.x >= 0.f ? e4.x : 0.2f * e4.x;
        e4.y = e4.y >= 0.f ? e4.y : 0.2f * e4.y;
        e4.z = e4.z >= 0.f ? e4.z : 0.2f * e4.z;
        e4.w = e4.w >= 0.f ? e4.w : 0.2f * e4.w;
        float4 w4;
        w4.x = __expf(e4.x); w4.y = __expf(e4.y); w4.z = __expf(e4.z); w4.w = __expf(e4.w);
        *(float4*)(wbuf + (size_t)eid * 4) = w4;
        sv.x += w4.x; sv.y += w4.y; sv.z += w4.z; sv.w += w4.w;
    }
    #pragma unroll
    for (int m = 32; m; m >>= 1) {
        sv.x += __shfl_xor(sv.x, m); sv.y += __shfl_xor(sv.y, m);
        sv.z += __shfl_xor(sv.z, m); sv.w += __shfl_xor(sv.w, m);
    }
    __threadfence_block();
    float4 rs;
    rs.x = 1.f / (sv.x + 1e-16f); rs.y = 1.f / (sv.y + 1e-16f);
    rs.z = 1.f / (sv.z + 1e-16f); rs.w = 1.f / (sv.w + 1e-16f);

    for (int j = lane; j < dg; j += 64) {
        const int eid = eidx[ro + j];
        const float4 w4 = *(const float4*)(wbuf + (size_t)eid * 4);
        float4 a4;
        a4.x = w4.x * rs.x; a4.y = w4.y * rs.y; a4.z = w4.z * rs.z; a4.w = w4.w * rs.w;
        *(float4*)(alpha_out + (size_t)eid * 4) = a4;
    }

    float4 rm;   // head-mean folded
    rm.x = 0.25f * rs.x; rm.y = 0.25f * rs.y; rm.z = 0.25f * rs.z; rm.w = 0.25f * rs.w;

    float acc = 0.f;
    for (int j0 = 0; j0 < dg; j0 += 64) {
        const int jn = min(64, dg - j0);
        int eid = 0, src = 0;
        if (lane < jn) { eid = eidx[ro + j0 + lane]; src = edges[eid].x; }
        for (int j = 0; j < jn; j++) {
            const int e_ = __shfl(eid, j);
            const int s_ = __shfl(src, j);
            const float4 w4 = *(const float4*)(wbuf + (size_t)e_ * 4);
            const unsigned short* hr = Hb + (size_t)s_ * 256 + lane;
            acc = fmaf(w4.x * rm.x, bfu(hr[0]),   acc);
            acc = fmaf(w4.y * rm.y, bfu(hr[64]),  acc);
            acc = fmaf(w4.z * rm.z, bfu(hr[128]), acc);
            acc = fmaf(w4.w * rm.w, bfu(hr[192]), acc);
        }
    }
    out[(size_t)node * 64 + lane] = acc + b3[lane];
}

extern "C" void kernel_launch(void* const* d_in, const int* in_sizes, int n_in,
                              void* d_out, int out_size, void* d_ws, size_t ws_size,
                              hipStream_t stream)
{
    char* ws = (char*)d_ws;
    unsigned short* Hb = (unsigned short*)(ws);   // [N,256] bf16 (layers 1/2: [N,128])
    float* xin    = (float*)(ws + 25600000);      // [N,128] f32
    float* xcur   = (float*)(ws + 51200000);      // [N,128]
    float* skip   = (float*)(ws + 76800000);      // [N,128]
    float* wbuf   = (float*)(ws + 102400000);     // [E,4]
    float* asb    = (float*)(ws + 128000000);     // [N,4]
    float* adb    = (float*)(ws + 128800000);     // [N,4]
    int2*  edges  = (int2*)(ws + 129600000);      // [E]
    int*   eidx   = (int*)(ws + 142400000);       // [E]
    int*   roff   = (int*)(ws + 148800000);       // [N]
    int*   deg    = (int*)(ws + 149000000);       // [N]
    int*   cursor = (int*)(ws + 149200000);       // [N]
    int*   flags  = (int*)(ws + 149400000);       // [2]
    float* wcvt   = (float*)(ws + 149400064);     // 83904 f32

    float* W1c  = wcvt;            float* Wsc  = wcvt + 16384;
    float* W2c  = wcvt + 32768;    float* W3c  = wcvt + 49152;
    float* as1c = wcvt + 81920;    float* ad1c = as1c + 128;
    float* b1c  = as1c + 256;      float* l1wc = as1c + 384;
    float* l1bc = as1c + 512;      float* bskc = as1c + 640;
    float* as2c = as1c + 768;      float* ad2c = as1c + 896;
    float* b2c  = as1c + 1024;     float* l2wc = as1c + 1152;
    float* l2bc = as1c + 1280;     float* as3c = as1c + 1408;
    float* ad3c = as1c + 1664;     float* b3c  = as1c + 1920;

    float* out = (float*)d_out;
    float* al1 = out + (size_t)NN * 64;
    float* al2 = al1 + (size_t)EE * 4;
    float* al3 = al2 + (size_t)EE * 4;

    // ---------------- normalize + CSR build ----------------
    detect_k<<<1, 256, 0, stream>>>(d_in[1], d_in[0], flags);
    hipMemsetAsync(deg, 0, NN * sizeof(int), stream);
    repack_k<<<6250, 256, 0, stream>>>(d_in[1], edges, deg, flags);
    cvt_all_k<<<25329, 256, 0, stream>>>(
        d_in[0], d_in[2], d_in[8], d_in[10], d_in[16],
        d_in[3], d_in[4], d_in[5], d_in[6], d_in[7],
        d_in[9], d_in[11], d_in[12], d_in[13], d_in[14], d_in[15],
        d_in[17], d_in[18], d_in[19],
        xin, wcvt, flags);
    scan_k<<<1, 256, 0, stream>>>(deg, roff, cursor);
    fill_k<<<6250, 256, 0, stream>>>(edges, cursor, eidx);

    // ---------------- layer 1 ----------------
    matmul_k<128, 32, true,  true ><<<6250, 256, 0, stream>>>(xin, W1c, as1c, ad1c, Hb, asb, adb);
    matmul_k<128, 32, false, false><<<6250, 256, 0, stream>>>(xin, Wsc, nullptr, nullptr, skip, nullptr, nullptr);
    fgather12_k<true><<<12500, 256, 0, stream>>>(roff, deg, eidx, edges, asb, adb, wbuf, Hb,
                                                 al1, b1c, l1wc, l1bc, skip, bskc, xcur);

    // ---------------- layer 2 ----------------
    matmul_k<128, 32, true, true><<<6250, 256, 0, stream>>>(xcur, W2c, as2c, ad2c, Hb, asb, adb);
    fgather12_k<false><<<12500, 256, 0, stream>>>(roff, deg, eidx, edges, asb, adb, wbuf, Hb,
                                                  al2, b2c, l2wc, l2bc, nullptr, nullptr, xcur);

    // ---------------- layer 3 ----------------
    matmul_k<256, 64, true, true><<<12500, 256, 0, stream>>>(xcur, W3c, as3c, ad3c, Hb, asb, adb);
    fgather3_k<<<12500, 256, 0, stream>>>(roff, deg, eidx, edges, asb, adb, wbuf, Hb,
                                          al3, b3c, out);
}

// Round 5
// 1240.677 us; speedup vs baseline: 10.4634x; 1.3227x over previous
//
#include <hip/hip_runtime.h>

#define NN 50000
#define EE 1600000

typedef __attribute__((ext_vector_type(8))) short bf16x8;
typedef __attribute__((ext_vector_type(4))) float f32x4;

__device__ __forceinline__ float bfu(unsigned short u) { return __uint_as_float((unsigned)u << 16); }
__device__ __forceinline__ unsigned short f2bf(float f) {   // RNE f32->bf16
    unsigned u = __float_as_uint(f);
    u += 0x7fff + ((u >> 16) & 1);
    return (unsigned short)(u >> 16);
}
__device__ __forceinline__ float cvt_load(const void* p, int i, bool f32) {
    if (f32) return ((const float*)p)[i];
    return bfu(((const unsigned short*)p)[i]);
}

// ---------------- dtype detection ----------------
__global__ void detect_k(const void* ei_raw, const void* x_raw, int* flags) {
    __shared__ int s_i64, s_f32;
    const int t = threadIdx.x;
    if (t == 0) { s_i64 = 1; s_f32 = 0; }
    __syncthreads();
    const int* ei32 = (const int*)ei_raw;
    if (ei32[2 * t + 1] != 0) atomicAnd(&s_i64, 0);
    const unsigned short* xu = (const unsigned short*)x_raw;
    int found = 0;
    for (int j = 0; j < 32; j++) {
        unsigned short u = xu[t * 32 + j];
        if ((u & 0x7F80) == 0x7F80) found = 1;
    }
    if (found) atomicOr(&s_f32, 1);
    __syncthreads();
    if (t == 0) { flags[0] = s_i64; flags[1] = s_f32; }
}

// ---------------- edge normalize -> int2 + degree ----------------
__global__ __launch_bounds__(256) void repack_k(const void* ei_raw, int2* edges,
                                                int* deg, const int* flags) {
    const int e = blockIdx.x * 256 + threadIdx.x;   // E exact
    const int i64 = __builtin_amdgcn_readfirstlane(flags[0]);
    int2 v;
    if (i64) {
        const long long* p = (const long long*)ei_raw;
        v.x = (int)p[e]; v.y = (int)p[EE + e];
    } else {
        const int* p = (const int*)ei_raw;
        v.x = p[e]; v.y = p[EE + e];
    }
    edges[e] = v;
    atomicAdd(&deg[v.y], 1);
}

// ---------------- CSR scan ----------------
__global__ __launch_bounds__(256) void scan_k(const int* __restrict__ deg,
                                              int* __restrict__ roff, int* __restrict__ cursor) {
    __shared__ int ps[256];
    const int t = threadIdx.x;
    const int CH = (NN + 255) / 256;
    const int lo = t * CH, hi = min(lo + CH, NN);
    int s = 0;
    for (int i = lo; i < hi; i++) s += deg[i];
    ps[t] = s;
    __syncthreads();
    for (int off = 1; off < 256; off <<= 1) {
        int v = (t >= off) ? ps[t - off] : 0;
        __syncthreads();
        ps[t] += v;
        __syncthreads();
    }
    int run = t ? ps[t - 1] : 0;
    for (int i = lo; i < hi; i++) { roff[i] = run; cursor[i] = run; run += deg[i]; }
}

// ---------------- CSR fill ----------------
__global__ __launch_bounds__(256) void fill_k(const int2* __restrict__ edges,
                                              int* cursor, int* __restrict__ eidx) {
    const int e = blockIdx.x * 256 + threadIdx.x;   // E exact
    const int p = atomicAdd(&cursor[edges[e].y], 1);
    eidx[p] = e;
}

// ---------------- normalize: x->bf16, W->transposed bf16, smalls->f32 ----------------
__global__ __launch_bounds__(256) void cvt_all_k(
    const void* x, const void* W1, const void* Wskip, const void* W2, const void* W3,
    const void* as1, const void* ad1, const void* b1, const void* l1w, const void* l1b,
    const void* bsk, const void* as2, const void* ad2, const void* b2, const void* l2w,
    const void* l2b, const void* as3, const void* ad3, const void* b3,
    unsigned short* xb, unsigned short* Wt1, unsigned short* Wts, unsigned short* Wt2,
    unsigned short* Wt3, float* smalls, const int* flags)
{
    const bool f32 = __builtin_amdgcn_readfirstlane(flags[1]) != 0;
    const int gid = blockIdx.x * 256 + threadIdx.x;
    if (gid < NN * 128) { xb[gid] = f2bf(cvt_load(x, gid, f32)); return; }
    int g = gid - NN * 128;
    if (g < 16384) { Wt1[g] = f2bf(cvt_load(W1,    (g & 127) * 128 + (g >> 7), f32)); return; }
    g -= 16384;
    if (g < 16384) { Wts[g] = f2bf(cvt_load(Wskip, (g & 127) * 128 + (g >> 7), f32)); return; }
    g -= 16384;
    if (g < 16384) { Wt2[g] = f2bf(cvt_load(W2,    (g & 127) * 128 + (g >> 7), f32)); return; }
    g -= 16384;
    if (g < 32768) { Wt3[g] = f2bf(cvt_load(W3,    (g & 127) * 256 + (g >> 7), f32)); return; }
    g -= 32768;
    if (g >= 2432) return;
    const void* src; int off;
    if      (g < 128)  { src = as1; off = g;        }
    else if (g < 256)  { src = ad1; off = g - 128;  }
    else if (g < 384)  { src = b1;  off = g - 256;  }
    else if (g < 512)  { src = l1w; off = g - 384;  }
    else if (g < 640)  { src = l1b; off = g - 512;  }
    else if (g < 768)  { src = bsk; off = g - 640;  }
    else if (g < 896)  { src = as2; off = g - 768;  }
    else if (g < 1024) { src = ad2; off = g - 896;  }
    else if (g < 1152) { src = b2;  off = g - 1024; }
    else if (g < 1280) { src = l2w; off = g - 1152; }
    else if (g < 1408) { src = l2b; off = g - 1280; }
    else if (g < 1664) { src = as3; off = g - 1408; }
    else if (g < 1920) { src = ad3; off = g - 1664; }
    else               { src = b3;  off = g - 1920; }
    smalls[g] = cvt_load(src, off, f32);
}

// ---------------- v_h = W3_h @ a3_h composites (for layer-3 logits) ----------------
__global__ void prep_v_k(const unsigned short* __restrict__ Wt3, const float* __restrict__ as3,
                         const float* __restrict__ ad3, float* __restrict__ vsrc, float* __restrict__ vdst)
{
    const int t = blockIdx.x * 256 + threadIdx.x;   // 512 total
    if (t >= 512) return;
    const int h = t >> 7, k = t & 127;
    float ss = 0.f, dd = 0.f;
    for (int c = 0; c < 64; c++) {
        const float w = bfu(Wt3[(size_t)(h * 64 + c) * 128 + k]);
        ss = fmaf(w, as3[h * 64 + c], ss);
        dd = fmaf(w, ad3[h * 64 + c], dd);
    }
    vsrc[t] = ss; vdst[t] = dd;
}

// ---------------- MFMA matmul: Hb[M,FOUT] = Xb[M,128] @ Wt^T (Wt is [FOUT,128]) ----------------
template<int FOUT>
__global__ __launch_bounds__(256) void mfma_mm_k(
    const unsigned short* __restrict__ Xb, const unsigned short* __restrict__ Wt,
    unsigned short* __restrict__ Hb)
{
    constexpr int NT = FOUT / 16;
    const int tile = blockIdx.x * 4 + (threadIdx.x >> 6);
    if (tile >= 3125) return;                       // 50000 = 3125*16
    const int l = threadIdx.x & 63;
    const int lr = l & 15, lq = l >> 4;
    const int m0 = tile * 16;
    f32x4 acc[NT];
    #pragma unroll
    for (int nt = 0; nt < NT; nt++) { acc[nt][0]=0.f; acc[nt][1]=0.f; acc[nt][2]=0.f; acc[nt][3]=0.f; }
    #pragma unroll
    for (int kb = 0; kb < 4; kb++) {                // K=128 = 4*32
        const bf16x8 a = *(const bf16x8*)(Xb + (size_t)(m0 + lr) * 128 + kb * 32 + lq * 8);
        #pragma unroll
        for (int nt = 0; nt < NT; nt++) {
            const bf16x8 b = *(const bf16x8*)(Wt + (size_t)(nt * 16 + lr) * 128 + kb * 32 + lq * 8);
            acc[nt] = __builtin_amdgcn_mfma_f32_16x16x32_bf16(a, b, acc[nt], 0, 0, 0);
        }
    }
    #pragma unroll
    for (int nt = 0; nt < NT; nt++)
        #pragma unroll
        for (int r = 0; r < 4; r++)
            Hb[(size_t)(m0 + lq * 4 + r) * FOUT + nt * 16 + lr] = f2bf(acc[nt][r]);
}

// ---------------- attention dots for layers 1/2 (FOUT=128, C=32) ----------------
__global__ __launch_bounds__(256) void dots_k(
    const unsigned short* __restrict__ Hb, const float* __restrict__ asrc,
    const float* __restrict__ adst, float* __restrict__ as_, float* __restrict__ ad_)
{
    const int node = blockIdx.x * 4 + (threadIdx.x >> 6);
    const int l = threadIdx.x & 63;
    const unsigned hv = *(const unsigned*)(Hb + (size_t)node * 128 + 2 * l);
    const float h0 = bfu((unsigned short)hv), h1 = bfu((unsigned short)(hv >> 16));
    const int hd = l >> 4;
    const int cc = (2 * l) & 31;
    float ps = h0 * asrc[hd * 32 + cc] + h1 * asrc[hd * 32 + cc + 1];
    float pd = h0 * adst[hd * 32 + cc] + h1 * adst[hd * 32 + cc + 1];
    #pragma unroll
    for (int m = 8; m; m >>= 1) { ps += __shfl_xor(ps, m); pd += __shfl_xor(pd, m); }
    if ((l & 15) == 0) {
        as_[(size_t)node * 4 + hd] = ps;
        ad_[(size_t)node * 4 + hd] = pd;
    }
}

// ---------------- layer-3 dots via composites: as3 = xcur . v_h ----------------
__global__ __launch_bounds__(256) void dots3_k(
    const unsigned short* __restrict__ Xb, const float* __restrict__ vsrc,
    const float* __restrict__ vdst, float* __restrict__ as_, float* __restrict__ ad_)
{
    const int node = blockIdx.x * 4 + (threadIdx.x >> 6);
    const int l = threadIdx.x & 63;
    const unsigned hv = *(const unsigned*)(Xb + (size_t)node * 128 + 2 * l);
    const float x0 = bfu((unsigned short)hv), x1 = bfu((unsigned short)(hv >> 16));
    float s[4], d[4];
    #pragma unroll
    for (int h = 0; h < 4; h++) {
        s[h] = x0 * vsrc[h * 128 + 2 * l] + x1 * vsrc[h * 128 + 2 * l + 1];
        d[h] = x0 * vdst[h * 128 + 2 * l] + x1 * vdst[h * 128 + 2 * l + 1];
    }
    #pragma unroll
    for (int m = 32; m; m >>= 1)
        #pragma unroll
        for (int h = 0; h < 4; h++) { s[h] += __shfl_xor(s[h], m); d[h] += __shfl_xor(d[h], m); }
    if (l == 0) {
        #pragma unroll
        for (int h = 0; h < 4; h++) {
            as_[(size_t)node * 4 + h] = s[h];
            ad_[(size_t)node * 4 + h] = d[h];
        }
    }
}

// ---------------- fused edge phase, layers 1/2 (gather bf16 H, epilogue, bf16 out) ----------------
template<bool HAS_SKIP>
__global__ __launch_bounds__(256) void fgather12_k(
    const int* __restrict__ roff, const int* __restrict__ deg, const int* __restrict__ eidx,
    const int2* __restrict__ edges, const float* __restrict__ as_, const float* __restrict__ ad_,
    float* __restrict__ wbuf, const unsigned short* __restrict__ Hb,
    float* __restrict__ alpha_out,
    const float* __restrict__ b, const float* __restrict__ lnw, const float* __restrict__ lnb,
    const unsigned short* __restrict__ skipb, const float* __restrict__ bskip,
    unsigned short* __restrict__ xoutb)
{
    const int node = blockIdx.x * 4 + (threadIdx.x >> 6);
    const int lane = threadIdx.x & 63;
    const int ro = roff[node], dg = deg[node];
    const float4 ad4 = *(const float4*)(ad_ + (size_t)node * 4);

    float4 sv = make_float4(0.f, 0.f, 0.f, 0.f);
    for (int j = lane; j < dg; j += 64) {
        const int eid = eidx[ro + j];
        const int src = edges[eid].x;
        float4 e4 = *(const float4*)(as_ + (size_t)src * 4);
        e4.x += ad4.x; e4.y += ad4.y; e4.z += ad4.z; e4.w += ad4.w;
        e4.x = e4.x >= 0.f ? e4.x : 0.2f * e4.x;
        e4.y = e4.y >= 0.f ? e4.y : 0.2f * e4.y;
        e4.z = e4.z >= 0.f ? e4.z : 0.2f * e4.z;
        e4.w = e4.w >= 0.f ? e4.w : 0.2f * e4.w;
        float4 w4;
        w4.x = __expf(e4.x); w4.y = __expf(e4.y); w4.z = __expf(e4.z); w4.w = __expf(e4.w);
        *(float4*)(wbuf + (size_t)eid * 4) = w4;
        sv.x += w4.x; sv.y += w4.y; sv.z += w4.z; sv.w += w4.w;
    }
    #pragma unroll
    for (int m = 32; m; m >>= 1) {
        sv.x += __shfl_xor(sv.x, m); sv.y += __shfl_xor(sv.y, m);
        sv.z += __shfl_xor(sv.z, m); sv.w += __shfl_xor(sv.w, m);
    }
    __threadfence_block();
    float4 rs;
    rs.x = 1.f / (sv.x + 1e-16f); rs.y = 1.f / (sv.y + 1e-16f);
    rs.z = 1.f / (sv.z + 1e-16f); rs.w = 1.f / (sv.w + 1e-16f);

    for (int j = lane; j < dg; j += 64) {
        const int eid = eidx[ro + j];
        const float4 w4 = *(const float4*)(wbuf + (size_t)eid * 4);
        float4 a4;
        a4.x = w4.x * rs.x; a4.y = w4.y * rs.y; a4.z = w4.z * rs.z; a4.w = w4.w * rs.w;
        *(float4*)(alpha_out + (size_t)eid * 4) = a4;
    }

    const int h = lane >> 4;
    const float rsh = (h == 0) ? rs.x : (h == 1) ? rs.y : (h == 2) ? rs.z : rs.w;
    float ax = 0.f, ay = 0.f;
    for (int j0 = 0; j0 < dg; j0 += 64) {
        const int jn = min(64, dg - j0);
        int eid = 0, src = 0;
        if (lane < jn) { eid = eidx[ro + j0 + lane]; src = edges[eid].x; }
        for (int j = 0; j < jn; j++) {
            const int e_ = __shfl(eid, j);
            const int s_ = __shfl(src, j);
            const float a = wbuf[(size_t)e_ * 4 + h] * rsh;
            const unsigned hv = *(const unsigned*)(Hb + (size_t)s_ * 128 + 2 * lane);
            ax = fmaf(a, bfu((unsigned short)hv), ax);
            ay = fmaf(a, bfu((unsigned short)(hv >> 16)), ay);
        }
    }

    float v0 = ax + b[2 * lane];
    float v1 = ay + b[2 * lane + 1];
    v0 = v0 > 0.f ? v0 : expm1f(v0);
    v1 = v1 > 0.f ? v1 : expm1f(v1);
    float s1 = v0 + v1, s2 = v0 * v0 + v1 * v1;
    #pragma unroll
    for (int m = 32; m; m >>= 1) { s1 += __shfl_xor(s1, m); s2 += __shfl_xor(s2, m); }
    const float mu   = s1 * (1.f / 128.f);
    const float var  = s2 * (1.f / 128.f) - mu * mu;
    const float rstd = rsqrtf(var + 1e-5f);
    float y0 = (v0 - mu) * rstd * lnw[2 * lane]     + lnb[2 * lane];
    float y1 = (v1 - mu) * rstd * lnw[2 * lane + 1] + lnb[2 * lane + 1];
    if (HAS_SKIP) {
        const unsigned sk = *(const unsigned*)(skipb + (size_t)node * 128 + 2 * lane);
        y0 += bfu((unsigned short)sk) + bskip[2 * lane];
        y1 += bfu((unsigned short)(sk >> 16)) + bskip[2 * lane + 1];
    }
    const unsigned pack = (unsigned)f2bf(y0) | ((unsigned)f2bf(y1) << 16);
    *(unsigned*)(xoutb + (size_t)node * 128 + 2 * lane) = pack;
}

// ---------------- layer-3 edge phase: gather xcur with per-head alpha -> g[N,4,128] bf16 ----------------
__global__ __launch_bounds__(256) void fgather3_k(
    const int* __restrict__ roff, const int* __restrict__ deg, const int* __restrict__ eidx,
    const int2* __restrict__ edges, const float* __restrict__ as_, const float* __restrict__ ad_,
    float* __restrict__ wbuf, const unsigned short* __restrict__ Xb,
    float* __restrict__ alpha_out, unsigned short* __restrict__ gout)
{
    const int node = blockIdx.x * 4 + (threadIdx.x >> 6);
    const int lane = threadIdx.x & 63;
    const int ro = roff[node], dg = deg[node];
    const float4 ad4 = *(const float4*)(ad_ + (size_t)node * 4);

    float4 sv = make_float4(0.f, 0.f, 0.f, 0.f);
    for (int j = lane; j < dg; j += 64) {
        const int eid = eidx[ro + j];
        const int src = edges[eid].x;
        float4 e4 = *(const float4*)(as_ + (size_t)src * 4);
        e4.x += ad4.x; e4.y += ad4.y; e4.z += ad4.z; e4.w += ad4.w;
        e4.x = e4.x >= 0.f ? e4.x : 0.2f * e4.x;
        e4.y = e4.y >= 0.f ? e4.y : 0.2f * e4.y;
        e4.z = e4.z >= 0.f ? e4.z : 0.2f * e4.z;
        e4.w = e4.w >= 0.f ? e4.w : 0.2f * e4.w;
        float4 w4;
        w4.x = __expf(e4.x); w4.y = __expf(e4.y); w4.z = __expf(e4.z); w4.w = __expf(e4.w);
        *(float4*)(wbuf + (size_t)eid * 4) = w4;
        sv.x += w4.x; sv.y += w4.y; sv.z += w4.z; sv.w += w4.w;
    }
    #pragma unroll
    for (int m = 32; m; m >>= 1) {
        sv.x += __shfl_xor(sv.x, m); sv.y += __shfl_xor(sv.y, m);
        sv.z += __shfl_xor(sv.z, m); sv.w += __shfl_xor(sv.w, m);
    }
    __threadfence_block();
    float4 rs;
    rs.x = 1.f / (sv.x + 1e-16f); rs.y = 1.f / (sv.y + 1e-16f);
    rs.z = 1.f / (sv.z + 1e-16f); rs.w = 1.f / (sv.w + 1e-16f);

    for (int j = lane; j < dg; j += 64) {
        const int eid = eidx[ro + j];
        const float4 w4 = *(const float4*)(wbuf + (size_t)eid * 4);
        float4 a4;
        a4.x = w4.x * rs.x; a4.y = w4.y * rs.y; a4.z = w4.z * rs.z; a4.w = w4.w * rs.w;
        *(float4*)(alpha_out + (size_t)eid * 4) = a4;
    }

    float a00 = 0.f, a01 = 0.f, a10 = 0.f, a11 = 0.f;
    float a20 = 0.f, a21 = 0.f, a30 = 0.f, a31 = 0.f;
    for (int j0 = 0; j0 < dg; j0 += 64) {
        const int jn = min(64, dg - j0);
        int eid = 0, src = 0;
        if (lane < jn) { eid = eidx[ro + j0 + lane]; src = edges[eid].x; }
        for (int j = 0; j < jn; j++) {
            const int e_ = __shfl(eid, j);
            const int s_ = __shfl(src, j);
            const float4 w4 = *(const float4*)(wbuf + (size_t)e_ * 4);
            const unsigned hv = *(const unsigned*)(Xb + (size_t)s_ * 128 + 2 * lane);
            const float x0 = bfu((unsigned short)hv), x1 = bfu((unsigned short)(hv >> 16));
            const float l0 = w4.x * rs.x, l1 = w4.y * rs.y, l2 = w4.z * rs.z, l3 = w4.w * rs.w;
            a00 = fmaf(l0, x0, a00); a01 = fmaf(l0, x1, a01);
            a10 = fmaf(l1, x0, a10); a11 = fmaf(l1, x1, a11);
            a20 = fmaf(l2, x0, a20); a21 = fmaf(l2, x1, a21);
            a30 = fmaf(l3, x0, a30); a31 = fmaf(l3, x1, a31);
        }
    }
    unsigned short* gr = gout + (size_t)node * 512 + 2 * lane;
    *(unsigned*)(gr)       = (unsigned)f2bf(a00) | ((unsigned)f2bf(a01) << 16);
    *(unsigned*)(gr + 128) = (unsigned)f2bf(a10) | ((unsigned)f2bf(a11) << 16);
    *(unsigned*)(gr + 256) = (unsigned)f2bf(a20) | ((unsigned)f2bf(a21) << 16);
    *(unsigned*)(gr + 384) = (unsigned)f2bf(a30) | ((unsigned)f2bf(a31) << 16);
}

// ---------------- layer-3 projection: out = 0.25 * g[N,512] @ Wstack + b3 (MFMA) ----------------
__global__ __launch_bounds__(256) void proj3_k(
    const unsigned short* __restrict__ Gb, const unsigned short* __restrict__ Wt3,
    const float* __restrict__ b3, float* __restrict__ out)
{
    const int tile = blockIdx.x * 4 + (threadIdx.x >> 6);
    if (tile >= 3125) return;
    const int l = threadIdx.x & 63;
    const int lr = l & 15, lq = l >> 4;
    const int m0 = tile * 16;
    f32x4 acc[4];
    #pragma unroll
    for (int nt = 0; nt < 4; nt++) { acc[nt][0]=0.f; acc[nt][1]=0.f; acc[nt][2]=0.f; acc[nt][3]=0.f; }
    #pragma unroll
    for (int kb = 0; kb < 16; kb++) {               // K=512
        const int h = kb >> 2;
        const int kk = (kb & 3) * 32 + lq * 8;      // k within [0,128)
        const bf16x8 a = *(const bf16x8*)(Gb + (size_t)(m0 + lr) * 512 + kb * 32 + lq * 8);
        #pragma unroll
        for (int nt = 0; nt < 4; nt++) {
            const int c = nt * 16 + lr;
            const bf16x8 b = *(const bf16x8*)(Wt3 + (size_t)(h * 64 + c) * 128 + kk);
            acc[nt] = __builtin_amdgcn_mfma_f32_16x16x32_bf16(a, b, acc[nt], 0, 0, 0);
        }
    }
    #pragma unroll
    for (int nt = 0; nt < 4; nt++)
        #pragma unroll
        for (int r = 0; r < 4; r++) {
            const int col = nt * 16 + lr;
            out[(size_t)(m0 + lq * 4 + r) * 64 + col] = 0.25f * acc[nt][r] + b3[col];
        }
}

extern "C" void kernel_launch(void* const* d_in, const int* in_sizes, int n_in,
                              void* d_out, int out_size, void* d_ws, size_t ws_size,
                              hipStream_t stream)
{
    char* ws = (char*)d_ws;
    unsigned short* g_bf    = (unsigned short*)(ws);              // [N,512] bf16
    float*          wbuf    = (float*)(ws + 51200000);            // [E,4] f32
    unsigned short* x_bf    = (unsigned short*)(ws + 76800000);   // [N,128] bf16
    unsigned short* xcur_bf = (unsigned short*)(ws + 89600000);   // [N,128] bf16
    unsigned short* skip_bf = (unsigned short*)(ws + 102400000);  // [N,128] bf16
    unsigned short* Hbuf    = (unsigned short*)(ws + 115200000);  // [N,128] bf16
    int2*  edges  = (int2*)(ws + 128000000);                      // [E]
    int*   eidx   = (int*)(ws + 140800000);                       // [E]
    float* asb    = (float*)(ws + 147200000);                     // [N,4]
    float* adb    = (float*)(ws + 148000000);                     // [N,4]
    int*   roff   = (int*)(ws + 148800000);
    int*   deg    = (int*)(ws + 149000000);
    int*   cursor = (int*)(ws + 149200000);
    int*   flags  = (int*)(ws + 149400000);
    unsigned short* Wt1 = (unsigned short*)(ws + 149400064);      // [128,128]
    unsigned short* Wts = Wt1 + 16384;
    unsigned short* Wt2 = Wts + 16384;
    unsigned short* Wt3 = Wt2 + 16384;                            // [256,128]
    float* smalls = (float*)(ws + 149563904);                     // 2432 f32
    float* vsrc   = (float*)(ws + 149573632);                     // [4,128]
    float* vdst   = (float*)(ws + 149575680);                     // [4,128]

    float* as1c = smalls;          float* ad1c = smalls + 128;
    float* b1c  = smalls + 256;    float* l1wc = smalls + 384;
    float* l1bc = smalls + 512;    float* bskc = smalls + 640;
    float* as2c = smalls + 768;    float* ad2c = smalls + 896;
    float* b2c  = smalls + 1024;   float* l2wc = smalls + 1152;
    float* l2bc = smalls + 1280;   float* as3c = smalls + 1408;
    float* ad3c = smalls + 1664;   float* b3c  = smalls + 1920;

    float* out = (float*)d_out;
    float* al1 = out + (size_t)NN * 64;
    float* al2 = al1 + (size_t)EE * 4;
    float* al3 = al2 + (size_t)EE * 4;

    // ---------------- normalize + CSR build ----------------
    detect_k<<<1, 256, 0, stream>>>(d_in[1], d_in[0], flags);
    hipMemsetAsync(deg, 0, NN * sizeof(int), stream);
    repack_k<<<6250, 256, 0, stream>>>(d_in[1], edges, deg, flags);
    cvt_all_k<<<25330, 256, 0, stream>>>(
        d_in[0], d_in[2], d_in[8], d_in[10], d_in[16],
        d_in[3], d_in[4], d_in[5], d_in[6], d_in[7],
        d_in[9], d_in[11], d_in[12], d_in[13], d_in[14], d_in[15],
        d_in[17], d_in[18], d_in[19],
        x_bf, Wt1, Wts, Wt2, Wt3, smalls, flags);
    scan_k<<<1, 256, 0, stream>>>(deg, roff, cursor);
    fill_k<<<6250, 256, 0, stream>>>(edges, cursor, eidx);
    prep_v_k<<<2, 256, 0, stream>>>(Wt3, as3c, ad3c, vsrc, vdst);

    // ---------------- layer 1 ----------------
    mfma_mm_k<128><<<782, 256, 0, stream>>>(x_bf, Wt1, Hbuf);
    mfma_mm_k<128><<<782, 256, 0, stream>>>(x_bf, Wts, skip_bf);
    dots_k<<<12500, 256, 0, stream>>>(Hbuf, as1c, ad1c, asb, adb);
    fgather12_k<true><<<12500, 256, 0, stream>>>(roff, deg, eidx, edges, asb, adb, wbuf, Hbuf,
                                                 al1, b1c, l1wc, l1bc, skip_bf, bskc, xcur_bf);

    // ---------------- layer 2 ----------------
    mfma_mm_k<128><<<782, 256, 0, stream>>>(xcur_bf, Wt2, Hbuf);
    dots_k<<<12500, 256, 0, stream>>>(Hbuf, as2c, ad2c, asb, adb);
    fgather12_k<false><<<12500, 256, 0, stream>>>(roff, deg, eidx, edges, asb, adb, wbuf, Hbuf,
                                                  al2, b2c, l2wc, l2bc, nullptr, nullptr, xcur_bf);

    // ---------------- layer 3 ----------------
    dots3_k<<<12500, 256, 0, stream>>>(xcur_bf, vsrc, vdst, asb, adb);
    fgather3_k<<<12500, 256, 0, stream>>>(roff, deg, eidx, edges, asb, adb, wbuf, xcur_bf,
                                          al3, g_bf);
    proj3_k<<<782, 256, 0, stream>>>(g_bf, Wt3, b3c, out);
}